// Round 2
// baseline (1671.050 us; speedup 1.0000x reference)
//
#include <hip/hip_runtime.h>

#define NN 512
#define BSZ 64
#define TTOT 200
#define NSTEP 199
#define DD 32

typedef __attribute__((ext_vector_type(8))) short bf16x8;
typedef __attribute__((ext_vector_type(4))) float f32x4;

__device__ __forceinline__ float bf2f(unsigned short u) {
  union { unsigned int i; float f; } v; v.i = ((unsigned int)u) << 16; return v.f;
}
__device__ __forceinline__ unsigned short f2bf(float f) {
  unsigned int b = __float_as_uint(f);
  unsigned int r = (b + 0x7fffu + ((b >> 16) & 1u)) >> 16;
  return (unsigned short)r;
}

// mode-generic loads: F32=1 -> input is float32; F32=0 -> input is bf16
template <int F32>
__device__ __forceinline__ float ldf(const void* p, size_t i) {
  if (F32) return ((const float*)p)[i];
  return bf2f(((const unsigned short*)p)[i]);
}
template <int F32>
__device__ __forceinline__ short ldbf(const void* p, size_t i) {
  if (F32) return (short)f2bf(((const float*)p)[i]);
  return (short)((const unsigned short*)p)[i];
}

// ---------------------------------------------------------------------------
// Dtype detector: node_embeddings is N(0,1). If the buffer is bf16, every
// even-index u16 is a bf16 value with |x| < ~6. If it is f32, even u16s are
// random mantissa words; over 256 samples the max |bf16(word)| is
// astronomically large with probability ~1. flag=1 -> f32 inputs.
// ---------------------------------------------------------------------------
__global__ void detect_kernel(const unsigned short* __restrict__ u, int* flag) {
  int t = threadIdx.x;
  float v = bf2f(u[2 * t]);
  float a = fabsf(v);
  int bad = (a < 1e6f) ? 0 : 1;  // NaN/inf also land here
  __shared__ int s;
  if (t == 0) s = 0;
  __syncthreads();
  if (bad) atomicOr(&s, 1);
  __syncthreads();
  if (t == 0) *flag = s;
}

// ---------------------------------------------------------------------------
// GEMM 1: A2[b] = A1[b] @ A1[b], bf16 out (row-major). LDS-free MFMA GEMM.
// a_frag: lane holds A[m=lane&15][k=quad*8+j];  b_frag: B[k=quad*8+j][n=lane&15]
// D: row=(lane>>4)*4+reg, col=lane&15   [m89/m91-verified]
// ---------------------------------------------------------------------------
template <int F32>
__global__ __launch_bounds__(256) void gemm_a2_kernel(
    const void* __restrict__ A1, unsigned short* __restrict__ A2,
    const int* __restrict__ flag) {
  if (*flag != F32) return;
  const int b = blockIdx.z, tm = blockIdx.y, tn = blockIdx.x;
  const int tid = threadIdx.x, lane = tid & 63, w = tid >> 6;
  const int q = lane >> 4, ln = lane & 15;
  const size_t Ao = (size_t)b * NN * NN;
  f32x4 zero = {0.f, 0.f, 0.f, 0.f};
  f32x4 acc[4] = {zero, zero, zero, zero};
  const size_t arow = (size_t)(tm * 64 + w * 16 + ln);
  for (int k0 = 0; k0 < NN; k0 += 32) {
    bf16x8 af;
    if (F32) {
      const float* ap = (const float*)A1 + Ao + arow * NN + k0 + q * 8;
      f32x4 x0 = *(const f32x4*)ap;
      f32x4 x1 = *(const f32x4*)(ap + 4);
#pragma unroll
      for (int j = 0; j < 4; ++j) {
        af[j] = (short)f2bf(x0[j]);
        af[4 + j] = (short)f2bf(x1[j]);
      }
    } else {
      af = *(const bf16x8*)((const unsigned short*)A1 + Ao + arow * NN + k0 + q * 8);
    }
#pragma unroll
    for (int i = 0; i < 4; ++i) {
      bf16x8 bv;
#pragma unroll
      for (int j = 0; j < 8; ++j)
        bv[j] = ldbf<F32>(A1, Ao + (size_t)(k0 + q * 8 + j) * NN + tn * 64 + i * 16 + ln);
      acc[i] = __builtin_amdgcn_mfma_f32_16x16x32_bf16(af, bv, acc[i], 0, 0, 0);
    }
  }
  unsigned short* Cb = A2 + Ao;
#pragma unroll
  for (int i = 0; i < 4; ++i) {
    int col = tn * 64 + i * 16 + ln;
#pragma unroll
    for (int r = 0; r < 4; ++r) {
      int row = tm * 64 + w * 16 + q * 4 + r;
      Cb[(size_t)row * NN + col] = f2bf(acc[i][r]);
    }
  }
}

// ---------------------------------------------------------------------------
// GEMM 2: A3 = A2 @ A1; epilogue M = c1*A1 + c2*A2 + c3*A3, scattered into
// B-fragment-blocked layout:
//   frag = (col>>4)*16 + (row>>5); slot l2 = ((row>>3)&3)*16 + (col&15);
//   elem = row&7;  addr = frag*512 + l2*8 + elem
// so the scan's b_frag is one 16B load per lane.
// ---------------------------------------------------------------------------
template <int F32>
__global__ __launch_bounds__(256) void gemm_m_kernel(
    const void* __restrict__ A1, const unsigned short* __restrict__ A2,
    unsigned short* __restrict__ Mfrag, const int* __restrict__ flag) {
  if (*flag != F32) return;
  const int b = blockIdx.z, tm = blockIdx.y, tn = blockIdx.x;
  const int tid = threadIdx.x, lane = tid & 63, w = tid >> 6;
  const int q = lane >> 4, ln = lane & 15;
  const size_t Ao = (size_t)b * NN * NN;
  const unsigned short* A2b = A2 + Ao;
  f32x4 zero = {0.f, 0.f, 0.f, 0.f};
  f32x4 acc[4] = {zero, zero, zero, zero};
  const size_t arow = (size_t)(tm * 64 + w * 16 + ln);
  for (int k0 = 0; k0 < NN; k0 += 32) {
    bf16x8 af = *(const bf16x8*)(A2b + arow * NN + k0 + q * 8);
#pragma unroll
    for (int i = 0; i < 4; ++i) {
      bf16x8 bv;
#pragma unroll
      for (int j = 0; j < 8; ++j)
        bv[j] = ldbf<F32>(A1, Ao + (size_t)(k0 + q * 8 + j) * NN + tn * 64 + i * 16 + ln);
      acc[i] = __builtin_amdgcn_mfma_f32_16x16x32_bf16(af, bv, acc[i], 0, 0, 0);
    }
  }
  const float c1 = 1.f / (3.f * 512.f * 512.f);
  const float c2 = c1 / 512.f;
  const float c3 = c2 / 512.f;
  unsigned short* Mb = Mfrag + Ao;
#pragma unroll
  for (int i = 0; i < 4; ++i) {
    int col = tn * 64 + i * 16 + ln;
#pragma unroll
    for (int r = 0; r < 4; ++r) {
      int row = tm * 64 + w * 16 + q * 4 + r;
      float mval = c1 * ldf<F32>(A1, Ao + (size_t)row * NN + col) +
                   c2 * bf2f(A2b[(size_t)row * NN + col]) + c3 * acc[i][r];
      int nt = col >> 4, cch = row >> 5;
      int l2 = ((row >> 3) & 3) * 16 + (col & 15);
      int jj = row & 7;
      Mb[(size_t)((nt * 16 + cch) * 512) + l2 * 8 + jj] = f2bf(mval);
    }
  }
}

// ---------------------------------------------------------------------------
// Scan: one block per batch (64 x 512 threads), 199 sequential steps.
// Thread t owns state column t. spatial matvec on the MFMA pipe with lp
// replicated into all 16 A-rows; lane takes acc[q][0] (= its own column).
// ---------------------------------------------------------------------------
template <int F32>
__global__ __launch_bounds__(512) void scan_kernel(
    const int* __restrict__ skills, const int* __restrict__ times,
    const void* __restrict__ labels, const void* __restrict__ emb,
    const void* __restrict__ user_b0, const void* __restrict__ user_f0,
    const void* __restrict__ w1g, const void* __restrict__ b1g,
    const void* __restrict__ w2g, const void* __restrict__ b2g,
    const void* __restrict__ wfg, const void* __restrict__ bfg,
    const void* __restrict__ wbg, const void* __restrict__ bbg,
    const unsigned short* __restrict__ Mfrag, void* __restrict__ out,
    const int* __restrict__ flag) {
  if (*flag != F32) return;
  const int b = blockIdx.x;
  const int t = threadIdx.x;
  const int lane = t & 63, w = t >> 6, q = lane >> 4;

  __shared__ float lp[NN];
  __shared__ __align__(16) unsigned short lpb[NN];
  __shared__ float nlf[NN];
  __shared__ float ub[2][DD], uf[2][DD];
  __shared__ float delta_s[NSTEP];
  __shared__ float label_s[NSTEP];
  __shared__ int skill_s[NSTEP];
  __shared__ float hp[16][33];
  __shared__ float w1t[DD * 5 * DD];
  __shared__ float w2t[DD * DD];
  __shared__ float wft[DD * DD], wbt[DD * DD];
  __shared__ float b1s[DD], b2s[DD], bfs[DD], bbs[DD];

  float nrec[DD], nsend[DD];
#pragma unroll
  for (int c = 0; c < DD; ++c) {
    nsend[c] = ldf<F32>(emb, (size_t)t * (2 * DD) + c);
    nrec[c] = ldf<F32>(emb, (size_t)t * (2 * DD) + DD + c);
  }
  for (int idx = t; idx < DD * DD * 5; idx += 512) {
    int o = idx / 160, rem = idx % 160;
    w1t[rem * 32 + o] = ldf<F32>(w1g, idx);
  }
  for (int idx = t; idx < DD * DD; idx += 512) {
    int o = idx >> 5, c = idx & 31;
    w2t[c * 32 + o] = ldf<F32>(w2g, idx);
    wft[c * 32 + o] = ldf<F32>(wfg, idx);
    wbt[c * 32 + o] = ldf<F32>(wbg, idx);
  }
  if (t < DD) {
    b1s[t] = ldf<F32>(b1g, t); b2s[t] = ldf<F32>(b2g, t);
    bfs[t] = ldf<F32>(bfg, t); bbs[t] = ldf<F32>(bbg, t);
    ub[0][t] = ldf<F32>(user_b0, b * DD + t);
    uf[0][t] = ldf<F32>(user_f0, b * DD + t);
  }
  for (int i = t; i < NSTEP; i += 512) {
    int dt_ = times[b * TTOT + i + 1] - times[b * TTOT + i];
    if (dt_ < 0) dt_ = -dt_;
    delta_s[i] = __logf((float)dt_ + 1e-6f) * 0.6213349345596119f;  // 1/ln 5
    label_s[i] = ldf<F32>(labels, b * TTOT + i + 1);
    skill_s[i] = skills[b * TTOT + i + 1];
  }
  __syncthreads();

  {
    float a = 0.f, f = 0.f;
#pragma unroll
    for (int c = 0; c < DD; ++c) {
      a += ub[0][c] * nrec[c];
      f += uf[0][c] * nsend[c];
    }
    lp[t] = a; lpb[t] = f2bf(a); nlf[t] = f;
  }
  __syncthreads();

  const unsigned short* Mb = Mfrag + (size_t)b * NN * NN;
  int p = 0;
  for (int step = 0; step < NSTEP; ++step) {
    // -------- Phase A (reads old state) --------
    f32x4 zero = {0.f, 0.f, 0.f, 0.f};
    f32x4 acc[4] = {zero, zero, zero, zero};
#pragma unroll 4
    for (int c = 0; c < 16; ++c) {
      bf16x8 af = *(const bf16x8*)(lpb + c * 32 + q * 8);
      const unsigned short* fb = Mb + ((size_t)(w * 64 + c) << 9);
#pragma unroll
      for (int i = 0; i < 4; ++i) {
        bf16x8 bv = *((const bf16x8*)(fb + (size_t)i * 8192) + lane);
        acc[i] = __builtin_amdgcn_mfma_f32_16x16x32_bf16(af, bv, acc[i], 0, 0, 0);
      }
    }
    float spatial = (q == 0) ? acc[0][0]
                  : (q == 1) ? acc[1][0]
                  : (q == 2) ? acc[2][0] : acc[3][0];

    float ncb = 0.f, nlfn = 0.f;
#pragma unroll
    for (int c = 0; c < DD; ++c) {
      ncb += ub[p][c] * nrec[c];
      nlfn += uf[p][c] * nsend[c];
    }
    float e = __expf(-delta_s[step] * 0.1f * nlf[t]) * lp[t];
    float x = ncb + e + spatial;
    float cur = 1.f / (1.f + __expf(-x));

    {
      int o = t & 31, s = t >> 5;
      float lab = label_s[step];
      int sk = skill_s[step];
      float hpart = 0.f;
#pragma unroll
      for (int cc = 0; cc < 2; ++cc) {
        int c = (s << 1) + cc;
        const float* wrow = &w1t[(c * 5) * 32 + o];
        float rs = ldf<F32>(emb, (size_t)sk * (2 * DD) + c);        // node_send
        float rr = ldf<F32>(emb, (size_t)sk * (2 * DD) + DD + c);   // node_rec
        hpart += ub[p][c] * wrow[0] + uf[p][c] * wrow[32] + lab * wrow[64] +
                 rr * wrow[96] + rs * wrow[128];
      }
      hp[s][o] = hpart;
    }
    __syncthreads();

    // -------- Phase B (writes new state) --------
    lp[t] = cur;
    lpb[t] = f2bf(cur);
    nlf[t] = nlfn;
    if (t == skill_s[step]) {
      if (F32) ((float*)out)[step * BSZ + b] = cur;
      else ((unsigned short*)out)[step * BSZ + b] = f2bf(cur);
    }

    if (t < DD) {
      int o = t;
      float h = b1s[o];
#pragma unroll
      for (int s = 0; s < 16; ++s) h += hp[s][o];
      h = fmaxf(h, 0.f);
      float uu = b2s[o];
#pragma unroll
      for (int c = 0; c < DD; ++c) uu += __shfl(h, c) * w2t[c * 32 + o];
      float fa = bfs[o], ba = bbs[o];
#pragma unroll
      for (int c = 0; c < DD; ++c) {
        float uc = __shfl(uu, c);
        fa += uc * wft[c * 32 + o];
        ba += uc * wbt[c * 32 + o];
      }
      float nf = 1.f - 2.f / (1.f + __expf(2.f * fa));
      float nb = 1.f - 2.f / (1.f + __expf(2.f * ba));
      uf[p ^ 1][o] = nf;
      ub[p ^ 1][o] = nb;
    }
    __syncthreads();
    p ^= 1;
  }
}

extern "C" void kernel_launch(void* const* d_in, const int* in_sizes, int n_in,
                              void* d_out, int out_size, void* d_ws, size_t ws_size,
                              hipStream_t stream) {
  (void)in_sizes; (void)n_in; (void)out_size; (void)ws_size;
  const int* skills = (const int*)d_in[0];
  const int* times = (const int*)d_in[1];

  int* flag = (int*)d_ws;
  unsigned short* A2 = (unsigned short*)((char*)d_ws + 256);       // 33.5 MB
  unsigned short* Mfrag = A2 + (size_t)BSZ * NN * NN;              // 33.5 MB

  detect_kernel<<<dim3(1), dim3(256), 0, stream>>>(
      (const unsigned short*)d_in[4], flag);

  dim3 gg(8, 8, BSZ), gb(256);
  gemm_a2_kernel<0><<<gg, gb, 0, stream>>>(d_in[3], A2, flag);
  gemm_a2_kernel<1><<<gg, gb, 0, stream>>>(d_in[3], A2, flag);
  gemm_m_kernel<0><<<gg, gb, 0, stream>>>(d_in[3], A2, Mfrag, flag);
  gemm_m_kernel<1><<<gg, gb, 0, stream>>>(d_in[3], A2, Mfrag, flag);

  dim3 sg(BSZ), sb(512);
  scan_kernel<0><<<sg, sb, 0, stream>>>(
      skills, times, d_in[2], d_in[4], d_in[5], d_in[6], d_in[7], d_in[8],
      d_in[9], d_in[10], d_in[11], d_in[12], d_in[13], d_in[14], Mfrag, d_out,
      flag);
  scan_kernel<1><<<sg, sb, 0, stream>>>(
      skills, times, d_in[2], d_in[4], d_in[5], d_in[6], d_in[7], d_in[8],
      d_in[9], d_in[10], d_in[11], d_in[12], d_in[13], d_in[14], Mfrag, d_out,
      flag);
}